// Round 10
// baseline (301.414 us; speedup 1.0000x reference)
//
#include <hip/hip_runtime.h>

#define NTOK 32768
#define SSTRIP 64                 // tokens per strip
#define QSTRIDE (256 * SSTRIP)    // q strip-tile elems: [256 chan][64 tok]

typedef __attribute__((ext_vector_type(8))) short  bf16x8;
typedef __attribute__((ext_vector_type(8))) unsigned short u16x8;
typedef __attribute__((ext_vector_type(4))) float  f32x4;

__device__ __forceinline__ unsigned short f32_to_bf16(float f) {
    unsigned int u = __float_as_uint(f);
    u += 0x7FFFu + ((u >> 16) & 1u);          // round-to-nearest-even
    return (unsigned short)(u >> 16);
}
__device__ __forceinline__ float bf16_to_f32(unsigned short h) {
    return __uint_as_float(((unsigned int)h) << 16);
}

// ---------------------------------------------------------------------------
// FUSED qkv GEMM + context (round 10).
// After 9 rounds, gemm1/gemm2 are pinned at ~1 TB/s effective regardless of
// occupancy / read pattern / write tiling / prefetch -> the only robust lever
// is deleting intermediate traffic. k and v are pure intermediates: this
// kernel computes the full qkv strip (64 toks x 768 chans), keeps exp(k) and
// v in LDS, and accumulates the per-head context num/den via MFMA + atomics
// in-kernel. Only q (32 MB) is written to HBM; the 64MB k/v write, 64MB ctx
// read, and the ctx dispatch disappear.
// Geometry: round-3/5-validated 64-tok strip, 4 waves (2m x 2n), wave =
// 64 chan x 32 tok, acc[4][2], swapped MFMA operands (lane m16 -> chan,
// quad*4+r -> tok), ushort4 stores. B (x) staged once to Bs (XOR swizzle).
// LDS: Bs 32KB + Ks 32KB + Vs 32KB = 96KB -> 1 block/CU (occupancy proven
// non-binding in rounds 1/5/7).
// chunks: mc 0,1 = q rows (softmax + store); mc 2,3 = k rows (exp -> Ks,
// den partials); mc 4,5 = v rows (-> Vs). Then one barrier, then per-wave
// 2 heads of ctx MFMA (num[d][e] += expk . v^T over 64 toks), atomicAdd.
// ---------------------------------------------------------------------------
__global__ __launch_bounds__(256) void qkv_ctx_kernel(
    const unsigned short* __restrict__ A,   // wqkv_bf [768][256]
    const float* __restrict__ X,            // x [b][256][NTOK]
    unsigned short* __restrict__ Q,         // q strip-tiled [b][512][256][64]
    float* __restrict__ num, float* __restrict__ den)
{
    const int bz = blockIdx.y;
    X += (long)bz * 256 * NTOK;
    Q += (long)bz * 256 * NTOK;             // 512 strips * QSTRIDE
    const int strip = blockIdx.x;
    const int col0 = strip * SSTRIP;

    __shared__ unsigned short Bs[SSTRIP * 256];   // [tok][256k]   32 KB
    __shared__ unsigned short Ks[256 * SSTRIP];   // [kchan][tok]  32 KB
    __shared__ unsigned short Vs[256 * SSTRIP];   // [vchan][tok]  32 KB

    const int t = threadIdx.x;
    const int wave = t >> 6, lane = t & 63;
    const int wm = wave >> 1, wn = wave & 1;
    const int m16 = lane & 15, quad = lane >> 4;

    // ---- stage B tile once: x [256k][64n] fp32 -> Bs[n][256k] bf16
    {
        const int n = t & 63;
        const int kg0 = (t >> 6) * 8;
        const int key = n & 7;
        const float* bcol = X + col0 + n;
        #pragma unroll
        for (int g = 0; g < 8; ++g) {
            const int kg = kg0 + g;
            unsigned short tmp[8];
            #pragma unroll
            for (int i = 0; i < 8; ++i)
                tmp[i] = f32_to_bf16(bcol[(size_t)(kg * 8 + i) * NTOK]);
            *(u16x8*)&Bs[n * 256 + ((kg ^ key) * 8)] = *(const u16x8*)tmp;
        }
    }
    __syncthreads();

    const int swk = m16 & 7;

    for (int mc = 0; mc < 6; ++mc) {
        const int m0 = mc * 128;
        f32x4 acc[4][2] = {};

        const unsigned short* Abase = A + (size_t)(m0 + wm * 64 + m16) * 256 + quad * 8;

        bf16x8 af_cur[4], af_nxt[4];
        #pragma unroll
        for (int mt = 0; mt < 4; ++mt)
            af_cur[mt] = *(const bf16x8*)&Abase[(size_t)mt * 16 * 256];

        #pragma unroll
        for (int kk = 0; kk < 8; ++kk) {
            if (kk < 7) {
                #pragma unroll
                for (int mt = 0; mt < 4; ++mt)
                    af_nxt[mt] = *(const bf16x8*)
                        &Abase[(size_t)mt * 16 * 256 + (kk + 1) * 32];
            }
            bf16x8 bf[2];
            #pragma unroll
            for (int nt = 0; nt < 2; ++nt) {
                const int col = wn * 32 + nt * 16 + m16;
                bf[nt] = *(const bf16x8*)&Bs[col * 256 + (((kk * 4 + quad) ^ swk) * 8)];
            }
            #pragma unroll
            for (int mt = 0; mt < 4; ++mt)
                #pragma unroll
                for (int nt = 0; nt < 2; ++nt)
                    acc[mt][nt] = __builtin_amdgcn_mfma_f32_16x16x32_bf16(
                        bf[nt], af_cur[mt], acc[mt][nt], 0, 0, 0);   // SWAPPED
            #pragma unroll
            for (int mt = 0; mt < 4; ++mt) af_cur[mt] = af_nxt[mt];
        }

        if (mc < 2) {
            // ---- q: softmax (mt pairs = heads) + store to strip-tiled Q
            #pragma unroll
            for (int hj = 0; hj < 2; ++hj) {
                #pragma unroll
                for (int nt = 0; nt < 2; ++nt) {
                    #pragma unroll
                    for (int r = 0; r < 4; ++r) {
                        float mx = fmaxf(acc[hj * 2][nt][r], acc[hj * 2 + 1][nt][r]);
                        mx = fmaxf(mx, __shfl_xor(mx, 1, 64));
                        mx = fmaxf(mx, __shfl_xor(mx, 2, 64));
                        mx = fmaxf(mx, __shfl_xor(mx, 4, 64));
                        mx = fmaxf(mx, __shfl_xor(mx, 8, 64));
                        const float e0 = __expf(acc[hj * 2][nt][r] - mx);
                        const float e1 = __expf(acc[hj * 2 + 1][nt][r] - mx);
                        float s = e0 + e1;
                        s += __shfl_xor(s, 1, 64);
                        s += __shfl_xor(s, 2, 64);
                        s += __shfl_xor(s, 4, 64);
                        s += __shfl_xor(s, 8, 64);
                        const float inv = 1.0f / s;
                        acc[hj * 2][nt][r]     = e0 * inv;
                        acc[hj * 2 + 1][nt][r] = e1 * inv;
                    }
                }
            }
            unsigned short* Qb = Q + (size_t)strip * QSTRIDE;
            #pragma unroll
            for (int mt = 0; mt < 4; ++mt) {
                const int row = m0 + wm * 64 + mt * 16 + m16;   // q chan 0..255
                #pragma unroll
                for (int nt = 0; nt < 2; ++nt) {
                    const int col = wn * 32 + nt * 16 + quad * 4;
                    ushort4 o;
                    o.x = f32_to_bf16(acc[mt][nt][0]);
                    o.y = f32_to_bf16(acc[mt][nt][1]);
                    o.z = f32_to_bf16(acc[mt][nt][2]);
                    o.w = f32_to_bf16(acc[mt][nt][3]);
                    *(ushort4*)&Qb[(size_t)row * SSTRIP + col] = o;
                }
            }
        } else if (mc < 4) {
            // ---- k: exp -> Ks (bf16), den partials from the ROUNDED values
            #pragma unroll
            for (int mt = 0; mt < 4; ++mt) {
                const int kchan = (m0 - 256) + wm * 64 + mt * 16 + m16;
                float dp = 0.f;
                #pragma unroll
                for (int nt = 0; nt < 2; ++nt) {
                    ushort4 o;
                    unsigned short eb;
                    #pragma unroll
                    for (int r = 0; r < 4; ++r) {
                        eb = f32_to_bf16(__expf(acc[mt][nt][r]));
                        dp += bf16_to_f32(eb);
                        ((unsigned short*)&o)[r] = eb;
                    }
                    const int col = wn * 32 + nt * 16 + quad * 4;
                    *(ushort4*)&Ks[(size_t)kchan * SSTRIP + col] = o;
                }
                dp += __shfl_xor(dp, 16, 64);
                dp += __shfl_xor(dp, 32, 64);
                if (quad == 0)
                    atomicAdd(&den[bz * 256 + kchan], dp);
            }
        } else {
            // ---- v: -> Vs (bf16)
            #pragma unroll
            for (int mt = 0; mt < 4; ++mt) {
                const int vchan = (m0 - 512) + wm * 64 + mt * 16 + m16;
                #pragma unroll
                for (int nt = 0; nt < 2; ++nt) {
                    ushort4 o;
                    o.x = f32_to_bf16(acc[mt][nt][0]);
                    o.y = f32_to_bf16(acc[mt][nt][1]);
                    o.z = f32_to_bf16(acc[mt][nt][2]);
                    o.w = f32_to_bf16(acc[mt][nt][3]);
                    const int col = wn * 32 + nt * 16 + quad * 4;
                    *(ushort4*)&Vs[(size_t)vchan * SSTRIP + col] = o;
                }
            }
        }
    }

    __syncthreads();   // Ks/Vs complete

    // ---- fused context: wave handles heads wave*2 + {0,1}
    // num[d][e] += sum_tok expk[d][tok] * v[e][tok]  (layout = ctx_mfma proven)
    #pragma unroll
    for (int hh = 0; hh < 2; ++hh) {
        const int h = wave * 2 + hh;
        f32x4 cacc[2][2] = {};
        #pragma unroll
        for (int ks = 0; ks < 2; ++ks) {
            bf16x8 kf[2], vf[2];
            #pragma unroll
            for (int dt = 0; dt < 2; ++dt)
                kf[dt] = *(const bf16x8*)
                    &Ks[(size_t)(h * 32 + dt * 16 + m16) * SSTRIP + ks * 32 + quad * 8];
            #pragma unroll
            for (int et = 0; et < 2; ++et)
                vf[et] = *(const bf16x8*)
                    &Vs[(size_t)(h * 32 + et * 16 + m16) * SSTRIP + ks * 32 + quad * 8];
            #pragma unroll
            for (int dt = 0; dt < 2; ++dt)
                #pragma unroll
                for (int et = 0; et < 2; ++et)
                    cacc[dt][et] = __builtin_amdgcn_mfma_f32_16x16x32_bf16(
                        kf[dt], vf[et], cacc[dt][et], 0, 0, 0);
        }
        float* nbase = num + ((long)(bz * 8 + h) * 32) * 32;
        #pragma unroll
        for (int dt = 0; dt < 2; ++dt)
            #pragma unroll
            for (int et = 0; et < 2; ++et)
                #pragma unroll
                for (int r = 0; r < 4; ++r)
                    atomicAdd(&nbase[(dt * 16 + quad * 4 + r) * 32 + et * 16 + m16],
                              cacc[dt][et][r]);
    }
}

// ---------------------------------------------------------------------------
// out GEMM: out[256][NTOK] = W2[256][256] @ q_soft (strip-tiled).
// 64-tok strips, B staged from strip-tiled Q (bf16 passthrough), flat C.
// ---------------------------------------------------------------------------
__global__ __launch_bounds__(256) void gemm_out(
    const unsigned short* __restrict__ A,   // W2 [b][256][256]
    const unsigned short* __restrict__ Q,   // q strip-tiled
    float* __restrict__ C)
{
    const int bz = blockIdx.y;
    A += (long)bz * 65536;
    Q += (long)bz * 256 * NTOK;
    C += (long)bz * 256 * NTOK;
    const int strip = blockIdx.x;
    const int col0 = strip * SSTRIP;

    __shared__ unsigned short Bs[SSTRIP * 256];   // 32 KB

    const int t = threadIdx.x;
    const int wave = t >> 6, lane = t & 63;
    const int wm = wave >> 1, wn = wave & 1;
    const int m16 = lane & 15, quad = lane >> 4;

    {
        const int n = t & 63;
        const int kg0 = (t >> 6) * 8;
        const int key = n & 7;
        const unsigned short* bcol = Q + (size_t)strip * QSTRIDE + n;
        #pragma unroll
        for (int g = 0; g < 8; ++g) {
            const int kg = kg0 + g;
            unsigned short tmp[8];
            #pragma unroll
            for (int i = 0; i < 8; ++i)
                tmp[i] = bcol[(size_t)(kg * 8 + i) * SSTRIP];
            *(u16x8*)&Bs[n * 256 + ((kg ^ key) * 8)] = *(const u16x8*)tmp;
        }
    }
    __syncthreads();

    const int swk = m16 & 7;

    for (int mc = 0; mc < 2; ++mc) {
        const int m0 = mc * 128;
        f32x4 acc[4][2] = {};
        const unsigned short* Abase = A + (size_t)(m0 + wm * 64 + m16) * 256 + quad * 8;

        bf16x8 af_cur[4], af_nxt[4];
        #pragma unroll
        for (int mt = 0; mt < 4; ++mt)
            af_cur[mt] = *(const bf16x8*)&Abase[(size_t)mt * 16 * 256];

        #pragma unroll
        for (int kk = 0; kk < 8; ++kk) {
            if (kk < 7) {
                #pragma unroll
                for (int mt = 0; mt < 4; ++mt)
                    af_nxt[mt] = *(const bf16x8*)
                        &Abase[(size_t)mt * 16 * 256 + (kk + 1) * 32];
            }
            bf16x8 bf[2];
            #pragma unroll
            for (int nt = 0; nt < 2; ++nt) {
                const int col = wn * 32 + nt * 16 + m16;
                bf[nt] = *(const bf16x8*)&Bs[col * 256 + (((kk * 4 + quad) ^ swk) * 8)];
            }
            #pragma unroll
            for (int mt = 0; mt < 4; ++mt)
                #pragma unroll
                for (int nt = 0; nt < 2; ++nt)
                    acc[mt][nt] = __builtin_amdgcn_mfma_f32_16x16x32_bf16(
                        bf[nt], af_cur[mt], acc[mt][nt], 0, 0, 0);
            #pragma unroll
            for (int mt = 0; mt < 4; ++mt) af_cur[mt] = af_nxt[mt];
        }

        #pragma unroll
        for (int mt = 0; mt < 4; ++mt) {
            const int row = m0 + wm * 64 + mt * 16 + m16;
            #pragma unroll
            for (int nt = 0; nt < 2; ++nt) {
                const int col = col0 + wn * 32 + nt * 16 + quad * 4;
                *(float4*)&C[(size_t)row * NTOK + col] = *(const float4*)&acc[mt][nt];
            }
        }
    }
}

// ---------------------------------------------------------------------------
// fp32 -> bf16 cast (vectorized)
// ---------------------------------------------------------------------------
__global__ __launch_bounds__(256) void cast_bf16_kernel(
    const float* __restrict__ src, unsigned short* __restrict__ dst, int n4)
{
    const int i = blockIdx.x * 256 + threadIdx.x;
    if (i < n4) {
        float4 v = ((const float4*)src)[i];
        ushort4 o;
        o.x = f32_to_bf16(v.x); o.y = f32_to_bf16(v.y);
        o.z = f32_to_bf16(v.z); o.w = f32_to_bf16(v.w);
        ((ushort4*)dst)[i] = o;
    }
}

// ---------------------------------------------------------------------------
// W2[b][o][h*32+d] = (sum_e w_out[o,h*32+e] * num[b,h,d,e]) / den[b,h*32+d]
// ---------------------------------------------------------------------------
__global__ __launch_bounds__(256) void combine_kernel(
    const float* __restrict__ w_out, const float* __restrict__ num,
    const float* __restrict__ den, unsigned short* __restrict__ W2)
{
    const int tid = blockIdx.x * 256 + threadIdx.x;   // 2*256*256 total
    const int b = tid >> 16;
    const int rem = tid & 65535;
    const int o = rem >> 8;
    const int i = rem & 255;
    const int h = i >> 5, d = i & 31;
    const float* wrow = w_out + o * 256 + h * 32;
    const float* nrow = num + (((long)(b * 8 + h) * 32 + d) << 5);
    float s = 0.f;
    #pragma unroll
    for (int e = 0; e < 32; ++e) s += wrow[e] * nrow[e];
    W2[tid] = f32_to_bf16(s / den[b * 256 + h * 32 + d]);
}

// ---------------------------------------------------------------------------
extern "C" void kernel_launch(void* const* d_in, const int* in_sizes, int n_in,
                              void* d_out, int out_size, void* d_ws, size_t ws_size,
                              hipStream_t stream)
{
    const float* x     = (const float*)d_in[0];   // [2,256,32768]
    const float* w_qkv = (const float*)d_in[1];   // [768,256]
    const float* w_out = (const float*)d_in[2];   // [256,256]
    float* out = (float*)d_out;                   // [2,256,32768]

    // workspace: q strip-tiled [b][512][256][64] bf16
    unsigned short* q_bf = (unsigned short*)d_ws;             // 2*256*32768 bf16
    unsigned short* wqkv_bf = q_bf + 2L * 256 * NTOK;         // 768*256 bf16
    unsigned short* W2 = wqkv_bf + 768 * 256;                 // 2*256*256 bf16
    float* num  = (float*)(W2 + 2 * 256 * 256);               // 16384
    float* den  = num + 16384;                                // 512

    hipMemsetAsync(num, 0, (16384 + 512) * sizeof(float), stream);

    // 0) cast w_qkv to bf16
    cast_bf16_kernel<<<192, 256, 0, stream>>>(w_qkv, wqkv_bf, 768 * 256 / 4);

    // 1) fused: qkv GEMM + q softmax + context num/den (k/v never hit HBM)
    qkv_ctx_kernel<<<dim3(NTOK / SSTRIP, 2), 256, 0, stream>>>(
        wqkv_bf, x, q_bf, num, den);

    // 2) W2 = fold(w_out, context) -> bf16
    combine_kernel<<<512, 256, 0, stream>>>(w_out, num, den, W2);

    // 3) out = W2 @ q_soft
    gemm_out<<<dim3(NTOK / SSTRIP, 2), 256, 0, stream>>>(W2, q_bf, out);
}